// Round 1
// baseline (1068.425 us; speedup 1.0000x reference)
//
#include <hip/hip_runtime.h>
#include <math.h>

#define BB 2
#define CC 512
#define NN 2304
#define NH 8
#define DH 64
#define DD 512
#define D3 1536
#define WIDTH 48

// ---------------------------------------------------------------------------
// Kernel 1: qkv[b,n,d] = sum_c x[b,c,n] * w_qkv[d,c], routed into
// q/k/v buffers laid out [b][h][n][dh].
// 64(n) x 64(d) tile per block, 256 threads, 4x4 register microtile.
// ---------------------------------------------------------------------------
__global__ __launch_bounds__(256) void qkv_gemm_k(
    const float* __restrict__ x, const float* __restrict__ w,
    float* __restrict__ qb, float* __restrict__ kb, float* __restrict__ vb)
{
  __shared__ float As[16][68];  // [c-chunk][n]
  __shared__ float Wt[16][68];  // [c-chunk][d]
  const int t = threadIdx.x;
  const int tx = t & 15, ty = t >> 4;
  const int n0 = blockIdx.x * 64;
  const int d0 = blockIdx.y * 64;
  const int b  = blockIdx.z;
  const float* xb = x + (size_t)b * CC * NN;
  float acc[4][4] = {};
  for (int c0 = 0; c0 < CC; c0 += 16) {
    {
      const int cc = t >> 4, ng = (t & 15) * 4;
      *(float4*)&As[cc][ng] =
          *(const float4*)(xb + (size_t)(c0 + cc) * NN + n0 + ng);
    }
    {
      const int dd = t >> 2, cg = (t & 3) * 4;
      float4 v = *(const float4*)(w + (size_t)(d0 + dd) * CC + c0 + cg);
      Wt[cg + 0][dd] = v.x; Wt[cg + 1][dd] = v.y;
      Wt[cg + 2][dd] = v.z; Wt[cg + 3][dd] = v.w;
    }
    __syncthreads();
#pragma unroll
    for (int cc = 0; cc < 16; ++cc) {
      float4 a4 = *(const float4*)&As[cc][tx * 4];
      float4 w4 = *(const float4*)&Wt[cc][ty * 4];
      float av[4] = {a4.x, a4.y, a4.z, a4.w};
      float wv[4] = {w4.x, w4.y, w4.z, w4.w};
#pragma unroll
      for (int i = 0; i < 4; ++i)
#pragma unroll
        for (int jj = 0; jj < 4; ++jj)
          acc[i][jj] += av[i] * wv[jj];
    }
    __syncthreads();
  }
  // d0 is a multiple of 64 -> whole tile maps to one of q/k/v and one head.
  const int which = d0 / DD;
  const int h = (d0 % DD) / DH;
  float* buf = which == 0 ? qb : (which == 1 ? kb : vb);
  const int dhb = ty * 4;
#pragma unroll
  for (int i = 0; i < 4; ++i) {
    const int n = n0 + tx * 4 + i;
    float4 o = {acc[i][0], acc[i][1], acc[i][2], acc[i][3]};
    *(float4*)(buf + (((size_t)b * NH + h) * NN + n) * DH + dhb) = o;
  }
}

// ---------------------------------------------------------------------------
// Kernel 2: flash-style fused attention per (b, h, 64-query tile).
// K/V chunks of 64 staged in LDS; P matrix reuses the K buffer (union) to
// keep static LDS at 3*64*68*4 = 52224 B. Online softmax with the Fresnel
// interference bias computed inline. Per-thread: 2 query rows x 8 keys
// (scores) and 2 rows x 8 dh (output accumulator).
// ---------------------------------------------------------------------------
__global__ __launch_bounds__(256) void attn_k(
    const float* __restrict__ qb, const float* __restrict__ kb,
    const float* __restrict__ vb, const float* __restrict__ wavp,
    float* __restrict__ ho)
{
  __shared__ float Qs[64][68];
  __shared__ float KPs[64][68];  // K chunk, then reused for P
  __shared__ float Vs[64][68];
  const int t = threadIdx.x;
  const int n0 = blockIdx.x * 64;
  const int h  = blockIdx.y;
  const int b  = blockIdx.z;
  const size_t base = ((size_t)b * NH + h) * NN * DH;
  const float* qp = qb + base;
  const float* kp = kb + base;
  const float* vp = vb + base;

  // stage Q tile (64 x 64)
#pragma unroll
  for (int r = 0; r < 4; ++r) {
    int idx = r * 256 + t;
    int row = idx >> 4, c4 = (idx & 15) * 4;
    *(float4*)&Qs[row][c4] =
        *(const float4*)(qp + (size_t)(n0 + row) * DH + c4);
  }

  const int j  = t & 7;        // key lane within row-group
  const int qq = t >> 3;       // row-group 0..31
  const int q0 = qq * 2, q1 = q0 + 1;
  const int qi0 = n0 + q0, qi1 = n0 + q1;
  const float y0 = (float)(qi0 / WIDTH), x0 = (float)(qi0 % WIDTH);
  const float y1 = (float)(qi1 / WIDTH), x1 = (float)(qi1 % WIDTH);
  const float wav = fabsf(wavp[0]);
  const float pc = 6.283185307179586f / (wav * (float)WIDTH + 1e-6f);

  float m0 = -INFINITY, m1 = -INFINITY;
  float l0 = 0.f, l1 = 0.f;
  float o0[8] = {}, o1[8] = {};

  __syncthreads();

  for (int k0 = 0; k0 < NN; k0 += 64) {
    // stage K and V chunks
#pragma unroll
    for (int r = 0; r < 4; ++r) {
      int idx = r * 256 + t;
      int row = idx >> 4, c4 = (idx & 15) * 4;
      *(float4*)&KPs[row][c4] =
          *(const float4*)(kp + (size_t)(k0 + row) * DH + c4);
      *(float4*)&Vs[row][c4] =
          *(const float4*)(vp + (size_t)(k0 + row) * DH + c4);
    }
    __syncthreads();

    // scores: 2 q-rows x 8 keys (keys k = j + 8m)
    float s0[8] = {}, s1[8] = {};
#pragma unroll
    for (int d4 = 0; d4 < 16; ++d4) {
      float4 qa = *(const float4*)&Qs[q0][d4 * 4];
      float4 qc = *(const float4*)&Qs[q1][d4 * 4];
#pragma unroll
      for (int m = 0; m < 8; ++m) {
        float4 kk = *(const float4*)&KPs[j + 8 * m][d4 * 4];
        s0[m] += qa.x * kk.x + qa.y * kk.y + qa.z * kk.z + qa.w * kk.w;
        s1[m] += qc.x * kk.x + qc.y * kk.y + qc.z * kk.z + qc.w * kk.w;
      }
    }
    // scale + Fresnel interference bias
#pragma unroll
    for (int m = 0; m < 8; ++m) {
      const int kj = k0 + j + 8 * m;
      const float yk = (float)(kj / WIDTH), xk = (float)(kj % WIDTH);
      {
        float dy = y0 - yk, dx = x0 - xk;
        float dist = sqrtf(dy * dy + dx * dx + 1e-8f);
        s0[m] = s0[m] * 0.125f + 0.1f * __cosf(dist * pc);
      }
      {
        float dy = y1 - yk, dx = x1 - xk;
        float dist = sqrtf(dy * dy + dx * dx + 1e-8f);
        s1[m] = s1[m] * 0.125f + 0.1f * __cosf(dist * pc);
      }
    }
    __syncthreads();  // all K reads done; KPs may now be overwritten with P

    // online softmax update (row-group of 8 lanes shares a pair of rows)
    float cm0 = s0[0], cm1 = s1[0];
#pragma unroll
    for (int m = 1; m < 8; ++m) { cm0 = fmaxf(cm0, s0[m]); cm1 = fmaxf(cm1, s1[m]); }
#pragma unroll
    for (int off = 1; off < 8; off <<= 1) {
      cm0 = fmaxf(cm0, __shfl_xor(cm0, off));
      cm1 = fmaxf(cm1, __shfl_xor(cm1, off));
    }
    const float nm0 = fmaxf(m0, cm0), nm1 = fmaxf(m1, cm1);
    const float a0 = __expf(m0 - nm0), a1 = __expf(m1 - nm1);
    float ps0 = 0.f, ps1 = 0.f;
#pragma unroll
    for (int m = 0; m < 8; ++m) {
      float p0 = __expf(s0[m] - nm0);
      float p1 = __expf(s1[m] - nm1);
      KPs[q0][j + 8 * m] = p0;
      KPs[q1][j + 8 * m] = p1;
      ps0 += p0; ps1 += p1;
    }
#pragma unroll
    for (int off = 1; off < 8; off <<= 1) {
      ps0 += __shfl_xor(ps0, off);
      ps1 += __shfl_xor(ps1, off);
    }
    l0 = l0 * a0 + ps0; m0 = nm0;
    l1 = l1 * a1 + ps1; m1 = nm1;
#pragma unroll
    for (int jj = 0; jj < 8; ++jj) { o0[jj] *= a0; o1[jj] *= a1; }
    __syncthreads();  // P visible to all

    // PV accumulate: this thread owns dh = j*8 .. j*8+7 for rows q0,q1
#pragma unroll
    for (int k4 = 0; k4 < 16; ++k4) {
      float4 p40 = *(const float4*)&KPs[q0][k4 * 4];
      float4 p41 = *(const float4*)&KPs[q1][k4 * 4];
      float pa0[4] = {p40.x, p40.y, p40.z, p40.w};
      float pa1[4] = {p41.x, p41.y, p41.z, p41.w};
#pragma unroll
      for (int kk = 0; kk < 4; ++kk) {
        const int krow = k4 * 4 + kk;
        float4 va  = *(const float4*)&Vs[krow][j * 8];
        float4 vb2 = *(const float4*)&Vs[krow][j * 8 + 4];
        o0[0] += pa0[kk] * va.x;  o0[1] += pa0[kk] * va.y;
        o0[2] += pa0[kk] * va.z;  o0[3] += pa0[kk] * va.w;
        o0[4] += pa0[kk] * vb2.x; o0[5] += pa0[kk] * vb2.y;
        o0[6] += pa0[kk] * vb2.z; o0[7] += pa0[kk] * vb2.w;
        o1[0] += pa1[kk] * va.x;  o1[1] += pa1[kk] * va.y;
        o1[2] += pa1[kk] * va.z;  o1[3] += pa1[kk] * va.w;
        o1[4] += pa1[kk] * vb2.x; o1[5] += pa1[kk] * vb2.y;
        o1[6] += pa1[kk] * vb2.z; o1[7] += pa1[kk] * vb2.w;
      }
    }
    __syncthreads();  // before next chunk overwrites KPs/Vs
  }

  const float inv0 = 1.f / l0, inv1 = 1.f / l1;
  float* hp0 = ho + ((size_t)b * NN + qi0) * DD + h * DH + j * 8;
  float* hp1 = ho + ((size_t)b * NN + qi1) * DD + h * DH + j * 8;
  float4 wa = {o0[0] * inv0, o0[1] * inv0, o0[2] * inv0, o0[3] * inv0};
  float4 wb = {o0[4] * inv0, o0[5] * inv0, o0[6] * inv0, o0[7] * inv0};
  float4 wc = {o1[0] * inv1, o1[1] * inv1, o1[2] * inv1, o1[3] * inv1};
  float4 wd = {o1[4] * inv1, o1[5] * inv1, o1[6] * inv1, o1[7] * inv1};
  *(float4*)(hp0)     = wa;
  *(float4*)(hp0 + 4) = wb;
  *(float4*)(hp1)     = wc;
  *(float4*)(hp1 + 4) = wd;
}

// ---------------------------------------------------------------------------
// Kernel 3: out[b,o,n] = sum_d ho[b,n,d] * w_out[o,d] + b_out[o]
// (writes d_out directly in [B][512][48*48] layout)
// ---------------------------------------------------------------------------
__global__ __launch_bounds__(256) void out_gemm_k(
    const float* __restrict__ ho, const float* __restrict__ w,
    const float* __restrict__ bias, float* __restrict__ out)
{
  __shared__ float Hs[16][68];  // [d-chunk][n]
  __shared__ float Ws[16][68];  // [d-chunk][o]
  const int t = threadIdx.x;
  const int tx = t & 15, ty = t >> 4;
  const int n0 = blockIdx.x * 64;
  const int o0 = blockIdx.y * 64;
  const int b  = blockIdx.z;
  float acc[4][4] = {};
  for (int d0 = 0; d0 < DD; d0 += 16) {
    {
      const int nn = t >> 2, dg = (t & 3) * 4;
      float4 v = *(const float4*)(ho + ((size_t)b * NN + n0 + nn) * DD + d0 + dg);
      Hs[dg + 0][nn] = v.x; Hs[dg + 1][nn] = v.y;
      Hs[dg + 2][nn] = v.z; Hs[dg + 3][nn] = v.w;
    }
    {
      const int oo = t >> 2, dg = (t & 3) * 4;
      float4 v = *(const float4*)(w + (size_t)(o0 + oo) * DD + d0 + dg);
      Ws[dg + 0][oo] = v.x; Ws[dg + 1][oo] = v.y;
      Ws[dg + 2][oo] = v.z; Ws[dg + 3][oo] = v.w;
    }
    __syncthreads();
#pragma unroll
    for (int dd = 0; dd < 16; ++dd) {
      float4 a4 = *(const float4*)&Hs[dd][tx * 4];
      float4 w4 = *(const float4*)&Ws[dd][ty * 4];
      float av[4] = {a4.x, a4.y, a4.z, a4.w};
      float wv[4] = {w4.x, w4.y, w4.z, w4.w};
#pragma unroll
      for (int i = 0; i < 4; ++i)
#pragma unroll
        for (int jj = 0; jj < 4; ++jj)
          acc[i][jj] += av[i] * wv[jj];
    }
    __syncthreads();
  }
#pragma unroll
  for (int jj = 0; jj < 4; ++jj) {
    const int o = o0 + ty * 4 + jj;
    const float bv = bias[o];
    float4 v = {acc[0][jj] + bv, acc[1][jj] + bv,
                acc[2][jj] + bv, acc[3][jj] + bv};
    *(float4*)(out + ((size_t)b * DD + o) * NN + n0 + tx * 4) = v;
  }
}

extern "C" void kernel_launch(void* const* d_in, const int* in_sizes, int n_in,
                              void* d_out, int out_size, void* d_ws, size_t ws_size,
                              hipStream_t stream)
{
  (void)in_sizes; (void)n_in; (void)out_size; (void)ws_size;
  const float* x     = (const float*)d_in[0];
  const float* w_qkv = (const float*)d_in[1];
  const float* w_out = (const float*)d_in[2];
  const float* b_out = (const float*)d_in[3];
  const float* wav   = (const float*)d_in[4];
  float* out = (float*)d_out;
  float* ws  = (float*)d_ws;

  const size_t SZ = (size_t)BB * NH * NN * DH;  // 2,359,296 floats per buffer
  float* qb = ws;
  float* kb = ws + SZ;
  float* vb = ws + 2 * SZ;
  float* ho = ws + 3 * SZ;  // [B][N][512]  -> total ws use: 4*SZ*4 = 37.75 MB

  qkv_gemm_k<<<dim3(NN / 64, D3 / 64, BB), 256, 0, stream>>>(x, w_qkv, qb, kb, vb);
  attn_k   <<<dim3(NN / 64, NH, BB),      256, 0, stream>>>(qb, kb, vb, wav, ho);
  out_gemm_k<<<dim3(NN / 64, DD / 64, BB), 256, 0, stream>>>(ho, w_out, b_out, out);
}

// Round 2
// 295.570 us; speedup vs baseline: 3.6148x; 3.6148x over previous
//
#include <hip/hip_runtime.h>
#include <math.h>

#define BB 2
#define CC 512
#define NN 2304
#define NH 8
#define DD 512
#define D3 1536
#define WIDTH 48

typedef _Float16 h8 __attribute__((ext_vector_type(8)));
typedef _Float16 h4 __attribute__((ext_vector_type(4)));
typedef float f4 __attribute__((ext_vector_type(4)));

// ---------------------------------------------------------------------------
// Kernel 0: Fresnel bias table bt[i][j] = 0.1*cos(2*pi*dist(i,j)/(|wav|*48+1e-6))
// Symmetric, f16. 2304x2304 = 10.6 MB.
// ---------------------------------------------------------------------------
__global__ __launch_bounds__(256) void bias_k(const float* __restrict__ wavp,
                                              _Float16* __restrict__ bt)
{
  const int j = blockIdx.x * 256 + threadIdx.x;
  const int i = blockIdx.y;
  const float pc = 6.283185307179586f / (fabsf(wavp[0]) * (float)WIDTH + 1e-6f);
  const float dy = (float)(i / WIDTH) - (float)(j / WIDTH);
  const float dx = (float)(i % WIDTH) - (float)(j % WIDTH);
  const float dist = sqrtf(dy * dy + dx * dx + 1e-8f);
  bt[(size_t)i * NN + j] = (_Float16)(0.1f * __cosf(dist * pc));
}

// ---------------------------------------------------------------------------
// Kernel 1: qkv = x^T * w_qkv^T (fp32 compute), outputs f16:
//   q,k : [b][h][n][dh]   (row-major, for MFMA A/B frags)
//   v   : [b][h][dh][n]   (TRANSPOSED, so attention PV reads V^T rows)
// ---------------------------------------------------------------------------
__global__ __launch_bounds__(256) void qkv_gemm_k(
    const float* __restrict__ x, const float* __restrict__ w,
    _Float16* __restrict__ qb, _Float16* __restrict__ kb, _Float16* __restrict__ vb)
{
  __shared__ float As[16][68];
  __shared__ float Wt[16][68];
  const int t = threadIdx.x;
  const int tx = t & 15, ty = t >> 4;
  const int n0 = blockIdx.x * 64;
  const int d0 = blockIdx.y * 64;
  const int b  = blockIdx.z;
  const float* xb = x + (size_t)b * CC * NN;
  float acc[4][4] = {};
  for (int c0 = 0; c0 < CC; c0 += 16) {
    {
      const int cc = t >> 4, ng = (t & 15) * 4;
      *(float4*)&As[cc][ng] =
          *(const float4*)(xb + (size_t)(c0 + cc) * NN + n0 + ng);
    }
    {
      const int dd = t >> 2, cg = (t & 3) * 4;
      float4 v = *(const float4*)(w + (size_t)(d0 + dd) * CC + c0 + cg);
      Wt[cg + 0][dd] = v.x; Wt[cg + 1][dd] = v.y;
      Wt[cg + 2][dd] = v.z; Wt[cg + 3][dd] = v.w;
    }
    __syncthreads();
#pragma unroll
    for (int cc = 0; cc < 16; ++cc) {
      float4 a4 = *(const float4*)&As[cc][tx * 4];
      float4 w4 = *(const float4*)&Wt[cc][ty * 4];
      float av[4] = {a4.x, a4.y, a4.z, a4.w};
      float wv[4] = {w4.x, w4.y, w4.z, w4.w};
#pragma unroll
      for (int i = 0; i < 4; ++i)
#pragma unroll
        for (int jj = 0; jj < 4; ++jj)
          acc[i][jj] += av[i] * wv[jj];
    }
    __syncthreads();
  }
  const int which = d0 / DD;
  const int h = (d0 % DD) / 64;
  const int dhb = ty * 4;
  if (which < 2) {
    _Float16* buf = which == 0 ? qb : kb;
#pragma unroll
    for (int i = 0; i < 4; ++i) {
      const int n = n0 + tx * 4 + i;
      h4 o = {(_Float16)acc[i][0], (_Float16)acc[i][1],
              (_Float16)acc[i][2], (_Float16)acc[i][3]};
      *(h4*)(buf + (((size_t)b * NH + h) * NN + n) * 64 + dhb) = o;
    }
  } else {
#pragma unroll
    for (int jj = 0; jj < 4; ++jj) {
      const int dh = dhb + jj;
      h4 o = {(_Float16)acc[0][jj], (_Float16)acc[1][jj],
              (_Float16)acc[2][jj], (_Float16)acc[3][jj]};
      *(h4*)(vb + (((size_t)b * NH + h) * 64 + dh) * NN + n0 + tx * 4) = o;
    }
  }
}

// ---------------------------------------------------------------------------
// Kernel 2: MFMA flash attention. Block = 128 thr (2 waves), q-tile 64
// (32 q/wave as 2 n-tiles). S^T = K*Q^T so softmax state is per-lane scalar
// (query on lane&15). O^T = V^T * P^T. Bias added from precomputed table.
// ---------------------------------------------------------------------------
__global__ __launch_bounds__(128, 2) void attn_k(
    const _Float16* __restrict__ qb, const _Float16* __restrict__ kb,
    const _Float16* __restrict__ vb, const _Float16* __restrict__ bt,
    float* __restrict__ ho)
{
  __shared__ _Float16 Ks[64][72];  // [key][dh]
  __shared__ _Float16 Vs[64][72];  // [dh][key]
  __shared__ _Float16 Bs[64][72];  // [query][key] bias tile
  __shared__ _Float16 Ps[64][72];  // [query][key] probabilities

  const int t    = threadIdx.x;
  const int lane = t & 63;
  const int w    = t >> 6;
  const int l15  = lane & 15;
  const int quad = lane >> 4;
  const int n0 = blockIdx.x * 64;
  const int h  = blockIdx.y;
  const int b  = blockIdx.z;
  const size_t base = ((size_t)b * NH + h) * NN * 64;
  const _Float16* qp = qb + base;
  const _Float16* kp = kb + base;
  const _Float16* vp = vb + base;  // [dh][n]

  // Q B-frags, register-resident for the whole kernel: qf[ntile][kstep]
  h8 qf[2][2];
#pragma unroll
  for (int nt = 0; nt < 2; ++nt)
#pragma unroll
    for (int ks = 0; ks < 2; ++ks)
      qf[nt][ks] = *(const h8*)(qp + (size_t)(n0 + w * 32 + nt * 16 + l15) * 64 +
                                ks * 32 + quad * 8);

  f4 oc[4][2];
#pragma unroll
  for (int mt = 0; mt < 4; ++mt)
#pragma unroll
    for (int nt = 0; nt < 2; ++nt) oc[mt][nt] = (f4)(0.f);
  float mx[2] = {-INFINITY, -INFINITY};
  float ls[2] = {0.f, 0.f};

  for (int k0 = 0; k0 < NN; k0 += 64) {
    // ---- stage K, V^T, bias tiles (global -> reg -> LDS) ----
    h8 kr[4], vr[4], br[4];
#pragma unroll
    for (int r = 0; r < 4; ++r) {
      const int c = t + r * 128;
      const int row = c >> 3, off = (c & 7) * 8;
      kr[r] = *(const h8*)(kp + (size_t)(k0 + row) * 64 + off);
      vr[r] = *(const h8*)(vp + (size_t)row * NN + k0 + off);
      br[r] = *(const h8*)(bt + (size_t)(n0 + row) * NN + k0 + off);
    }
    __syncthreads();  // prior iteration's LDS reads complete
#pragma unroll
    for (int r = 0; r < 4; ++r) {
      const int c = t + r * 128;
      const int row = c >> 3, off = (c & 7) * 8;
      *(h8*)&Ks[row][off] = kr[r];
      *(h8*)&Vs[row][off] = vr[r];
      *(h8*)&Bs[row][off] = br[r];
    }
    __syncthreads();

    // ---- S^T = K * Q^T  (row=key, col=query) ----
    f4 st[4][2];
#pragma unroll
    for (int mt = 0; mt < 4; ++mt)
#pragma unroll
      for (int nt = 0; nt < 2; ++nt) st[mt][nt] = (f4)(0.f);
#pragma unroll
    for (int ks = 0; ks < 2; ++ks) {
#pragma unroll
      for (int mt = 0; mt < 4; ++mt) {
        h8 kf = *(const h8*)&Ks[mt * 16 + l15][ks * 32 + quad * 8];
#pragma unroll
        for (int nt = 0; nt < 2; ++nt)
          st[mt][nt] = __builtin_amdgcn_mfma_f32_16x16x32_f16(
              kf, qf[nt][ks], st[mt][nt], 0, 0, 0);
      }
    }

    // ---- scale + bias + online softmax (per-lane query scalar) ----
#pragma unroll
    for (int nt = 0; nt < 2; ++nt) {
      const int q = w * 32 + nt * 16 + l15;  // query row within tile
      float lg[4][4];
      float rowmax = -INFINITY;
#pragma unroll
      for (int mt = 0; mt < 4; ++mt) {
        h4 bv = *(const h4*)&Bs[q][mt * 16 + quad * 4];
#pragma unroll
        for (int r = 0; r < 4; ++r) {
          float v = st[mt][nt][r] * 0.125f + (float)bv[r];
          lg[mt][r] = v;
          rowmax = fmaxf(rowmax, v);
        }
      }
      rowmax = fmaxf(rowmax, __shfl_xor(rowmax, 16));
      rowmax = fmaxf(rowmax, __shfl_xor(rowmax, 32));
      const float mnew = fmaxf(mx[nt], rowmax);
      const float alpha = __expf(mx[nt] - mnew);
      mx[nt] = mnew;
      float psum = 0.f;
#pragma unroll
      for (int mt = 0; mt < 4; ++mt) {
        h4 pk;
#pragma unroll
        for (int r = 0; r < 4; ++r) {
          float p = __expf(lg[mt][r] - mnew);
          psum += p;
          pk[r] = (_Float16)p;
        }
        *(h4*)&Ps[q][mt * 16 + quad * 4] = pk;  // 4 consecutive keys
      }
      psum += __shfl_xor(psum, 16);
      psum += __shfl_xor(psum, 32);
      ls[nt] = ls[nt] * alpha + psum;
#pragma unroll
      for (int mt = 0; mt < 4; ++mt)
#pragma unroll
        for (int r = 0; r < 4; ++r) oc[mt][nt][r] *= alpha;
    }
    // P rows are wave-private: no block barrier needed before PV.

    // ---- O^T += V^T * P^T ----
#pragma unroll
    for (int ks = 0; ks < 2; ++ks) {
      h8 pf[2];
#pragma unroll
      for (int nt = 0; nt < 2; ++nt)
        pf[nt] = *(const h8*)&Ps[w * 32 + nt * 16 + l15][ks * 32 + quad * 8];
#pragma unroll
      for (int mt = 0; mt < 4; ++mt) {
        h8 vf = *(const h8*)&Vs[mt * 16 + l15][ks * 32 + quad * 8];
#pragma unroll
        for (int nt = 0; nt < 2; ++nt)
          oc[mt][nt] = __builtin_amdgcn_mfma_f32_16x16x32_f16(
              vf, pf[nt], oc[mt][nt], 0, 0, 0);
      }
    }
  }

  // ---- epilogue: normalize, write ho[b][n][h*64+dh] fp32 ----
#pragma unroll
  for (int nt = 0; nt < 2; ++nt) {
    const float inv = 1.f / ls[nt];
    const int qi = n0 + w * 32 + nt * 16 + l15;
#pragma unroll
    for (int mt = 0; mt < 4; ++mt) {
      const int dh = mt * 16 + quad * 4;
      float4 o = {oc[mt][nt][0] * inv, oc[mt][nt][1] * inv,
                  oc[mt][nt][2] * inv, oc[mt][nt][3] * inv};
      *(float4*)(ho + ((size_t)b * NN + qi) * DD + h * 64 + dh) = o;
    }
  }
}

// ---------------------------------------------------------------------------
// Kernel 3: out[b,o,n] = sum_d ho[b,n,d] * w_out[o,d] + b_out[o]  (fp32)
// ---------------------------------------------------------------------------
__global__ __launch_bounds__(256) void out_gemm_k(
    const float* __restrict__ ho, const float* __restrict__ w,
    const float* __restrict__ bias, float* __restrict__ out)
{
  __shared__ float Hs[16][68];
  __shared__ float Ws[16][68];
  const int t = threadIdx.x;
  const int tx = t & 15, ty = t >> 4;
  const int n0 = blockIdx.x * 64;
  const int o0 = blockIdx.y * 64;
  const int b  = blockIdx.z;
  float acc[4][4] = {};
  for (int d0 = 0; d0 < DD; d0 += 16) {
    {
      const int nn = t >> 2, dg = (t & 3) * 4;
      float4 v = *(const float4*)(ho + ((size_t)b * NN + n0 + nn) * DD + d0 + dg);
      Hs[dg + 0][nn] = v.x; Hs[dg + 1][nn] = v.y;
      Hs[dg + 2][nn] = v.z; Hs[dg + 3][nn] = v.w;
    }
    {
      const int oo = t >> 2, dg = (t & 3) * 4;
      float4 v = *(const float4*)(w + (size_t)(o0 + oo) * DD + d0 + dg);
      Ws[dg + 0][oo] = v.x; Ws[dg + 1][oo] = v.y;
      Ws[dg + 2][oo] = v.z; Ws[dg + 3][oo] = v.w;
    }
    __syncthreads();
#pragma unroll
    for (int dd = 0; dd < 16; ++dd) {
      float4 a4 = *(const float4*)&Hs[dd][tx * 4];
      float4 w4 = *(const float4*)&Ws[dd][ty * 4];
      float av[4] = {a4.x, a4.y, a4.z, a4.w};
      float wv[4] = {w4.x, w4.y, w4.z, w4.w};
#pragma unroll
      for (int i = 0; i < 4; ++i)
#pragma unroll
        for (int jj = 0; jj < 4; ++jj)
          acc[i][jj] += av[i] * wv[jj];
    }
    __syncthreads();
  }
#pragma unroll
  for (int jj = 0; jj < 4; ++jj) {
    const int o = o0 + ty * 4 + jj;
    const float bv = bias[o];
    float4 v = {acc[0][jj] + bv, acc[1][jj] + bv,
                acc[2][jj] + bv, acc[3][jj] + bv};
    *(float4*)(out + ((size_t)b * DD + o) * NN + n0 + tx * 4) = v;
  }
}

extern "C" void kernel_launch(void* const* d_in, const int* in_sizes, int n_in,
                              void* d_out, int out_size, void* d_ws, size_t ws_size,
                              hipStream_t stream)
{
  (void)in_sizes; (void)n_in; (void)out_size; (void)ws_size;
  const float* x     = (const float*)d_in[0];
  const float* w_qkv = (const float*)d_in[1];
  const float* w_out = (const float*)d_in[2];
  const float* b_out = (const float*)d_in[3];
  const float* wav   = (const float*)d_in[4];
  float* out = (float*)d_out;

  const size_t SZ = (size_t)BB * NH * NN * 64;  // 2,359,296 f16 per q/k/v buffer
  _Float16* qb = (_Float16*)d_ws;
  _Float16* kb = qb + SZ;
  _Float16* vb = kb + SZ;
  _Float16* bt = vb + SZ;                      // 2304*2304 f16 bias table
  float*    ho = (float*)(bt + (size_t)NN * NN);  // [B][N][512] fp32
  // total ws use: 3*4.5MB + 10.1MB + 9MB = ~33.8 MB (< 37.75 MB used in R1)

  bias_k    <<<dim3(NN / 256, NN), 256, 0, stream>>>(wav, bt);
  qkv_gemm_k<<<dim3(NN / 64, D3 / 64, BB), 256, 0, stream>>>(x, w_qkv, qb, kb, vb);
  attn_k    <<<dim3(NN / 64, NH, BB), 128, 0, stream>>>(qb, kb, vb, bt, ho);
  out_gemm_k<<<dim3(NN / 64, DD / 64, BB), 256, 0, stream>>>(ho, w_out, b_out, out);
}

// Round 3
// 191.061 us; speedup vs baseline: 5.5921x; 1.5470x over previous
//
#include <hip/hip_runtime.h>
#include <math.h>

#define BB 2
#define CC 512
#define NN 2304
#define NH 8
#define DD 512
#define D3 1536
#define WIDTH 48

typedef _Float16 h8 __attribute__((ext_vector_type(8)));
typedef _Float16 h4 __attribute__((ext_vector_type(4)));
typedef _Float16 h2 __attribute__((ext_vector_type(2)));
typedef float f4 __attribute__((ext_vector_type(4)));

__device__ __forceinline__ void gload16(const void* g, void* s) {
  __builtin_amdgcn_global_load_lds(
      (const __attribute__((address_space(1))) unsigned int*)g,
      (__attribute__((address_space(3))) unsigned int*)s, 16, 0, 0);
}

// ---------------------------------------------------------------------------
// Kernel 0: Fresnel bias table bt[i][j] = 0.1*cos(2*pi*dist/(|wav|*48+1e-6))
// ---------------------------------------------------------------------------
__global__ __launch_bounds__(256) void bias_k(const float* __restrict__ wavp,
                                              _Float16* __restrict__ bt)
{
  const int j = blockIdx.x * 256 + threadIdx.x;
  const int i = blockIdx.y;
  const float pc = 6.283185307179586f / (fabsf(wavp[0]) * (float)WIDTH + 1e-6f);
  const float dy = (float)(i / WIDTH) - (float)(j / WIDTH);
  const float dx = (float)(i % WIDTH) - (float)(j % WIDTH);
  const float dist = sqrtf(dy * dy + dx * dx + 1e-8f);
  bt[(size_t)i * NN + j] = (_Float16)(0.1f * __cosf(dist * pc));
}

// ---------------------------------------------------------------------------
// Kernel 0b: transpose-convert x[b][c][n] fp32 -> xt[b][n][c] f16
// ---------------------------------------------------------------------------
__global__ __launch_bounds__(256) void tx_k(const float* __restrict__ x,
                                            _Float16* __restrict__ xt)
{
  __shared__ float Ls[32][33];
  const int t = threadIdx.x;
  const int n0 = blockIdx.x * 32, c0 = blockIdx.y * 32, b = blockIdx.z;
#pragma unroll
  for (int p = 0; p < 4; ++p) {
    const int cl = (t >> 5) + p * 8, nl = t & 31;
    Ls[cl][nl] = x[((size_t)b * CC + c0 + cl) * NN + n0 + nl];
  }
  __syncthreads();
#pragma unroll
  for (int p = 0; p < 2; ++p) {
    const int nl = (t >> 4) + p * 16, cl = (t & 15) * 2;
    h2 v = {(_Float16)Ls[cl][nl], (_Float16)Ls[cl + 1][nl]};
    *(h2*)(xt + ((size_t)b * NN + n0 + nl) * CC + c0 + cl) = v;
  }
}

// ---------------------------------------------------------------------------
// Kernel 0c: convert w_qkv [1536][512] and w_out [512][512] fp32 -> f16
// ---------------------------------------------------------------------------
__global__ __launch_bounds__(256) void convw_k(const float* __restrict__ wq,
                                               const float* __restrict__ wo,
                                               _Float16* __restrict__ wqh,
                                               _Float16* __restrict__ woh)
{
  const int idx = blockIdx.x * 256 + threadIdx.x;
  const int NQ = (D3 * CC) / 4;  // 196608 float4 quads
  if (idx < NQ) {
    float4 v = *(const float4*)(wq + (size_t)idx * 4);
    h4 o = {(_Float16)v.x, (_Float16)v.y, (_Float16)v.z, (_Float16)v.w};
    *(h4*)(wqh + (size_t)idx * 4) = o;
  } else {
    const int j = idx - NQ;
    float4 v = *(const float4*)(wo + (size_t)j * 4);
    h4 o = {(_Float16)v.x, (_Float16)v.y, (_Float16)v.z, (_Float16)v.w};
    *(h4*)(woh + (size_t)j * 4) = o;
  }
}

// ---------------------------------------------------------------------------
// Kernel 1: qkv MFMA GEMM. qkv[n][d] = sum_c xt[n][c] * w[d][c].
// 128(token) x 128(d) tile, 4 waves (2x2 of 64x64), BK=32, f16 MFMA.
// q/k blocks: D[d][token] (acc packs along dh -> [n][dh] stores).
// v blocks:   D[token][d] via swapped MFMA args (packs along n -> [dh][n]).
// ---------------------------------------------------------------------------
__global__ __launch_bounds__(256) void qkv_gemm_k(
    const _Float16* __restrict__ xt, const _Float16* __restrict__ wqh,
    _Float16* __restrict__ qb, _Float16* __restrict__ kb,
    _Float16* __restrict__ vb)
{
  __shared__ _Float16 Xs[128][32];
  __shared__ _Float16 Ws[128][32];
  const int t = threadIdx.x;
  const int lane = t & 63, w = t >> 6;
  const int l15 = lane & 15, quad = lane >> 4;
  const int wm = w & 1, wn = w >> 1;
  const int n0 = blockIdx.x * 128;
  const int d0 = blockIdx.y * 128;
  const int b  = blockIdx.z;
  const bool isv = (d0 >= 2 * DD);
  const _Float16* xb = xt + (size_t)b * NN * CC;

  const int srow = lane >> 2, scol = (lane & 3) * 8;

  f4 acc[4][4];
#pragma unroll
  for (int mt = 0; mt < 4; ++mt)
#pragma unroll
    for (int nt = 0; nt < 4; ++nt) acc[mt][nt] = (f4)(0.f);

  for (int c0 = 0; c0 < CC; c0 += 32) {
    // stage both tiles: 8 chunks of 1KB each buffer, wave w takes {w, w+4}
#pragma unroll
    for (int r = 0; r < 2; ++r) {
      const int ci = w + r * 4;
      const int row = ci * 16 + srow;
      gload16(xb + (size_t)(n0 + row) * CC + c0 + scol, &Xs[0][0] + ci * 512);
      gload16(wqh + (size_t)(d0 + row) * CC + c0 + scol, &Ws[0][0] + ci * 512);
    }
    __syncthreads();

    h8 wfr[4], xfr[4];
#pragma unroll
    for (int mt = 0; mt < 4; ++mt)
      wfr[mt] = *(const h8*)&Ws[wm * 64 + mt * 16 + l15][quad * 8];
#pragma unroll
    for (int nt = 0; nt < 4; ++nt)
      xfr[nt] = *(const h8*)&Xs[wn * 64 + nt * 16 + l15][quad * 8];

    if (!isv) {
#pragma unroll
      for (int mt = 0; mt < 4; ++mt)
#pragma unroll
        for (int nt = 0; nt < 4; ++nt)
          acc[mt][nt] = __builtin_amdgcn_mfma_f32_16x16x32_f16(
              wfr[mt], xfr[nt], acc[mt][nt], 0, 0, 0);
    } else {
#pragma unroll
      for (int mt = 0; mt < 4; ++mt)
#pragma unroll
        for (int nt = 0; nt < 4; ++nt)
          acc[mt][nt] = __builtin_amdgcn_mfma_f32_16x16x32_f16(
              xfr[nt], wfr[mt], acc[mt][nt], 0, 0, 0);
    }
    __syncthreads();
  }

  if (!isv) {
    const int which = d0 >> 9;  // 0 = q, 1 = k
    _Float16* buf = which == 0 ? qb : kb;
    const int h = ((d0 & 511) >> 6) + wm;
#pragma unroll
    for (int mt = 0; mt < 4; ++mt) {
      const int dh = mt * 16 + quad * 4;
#pragma unroll
      for (int nt = 0; nt < 4; ++nt) {
        const int token = n0 + wn * 64 + nt * 16 + l15;
        h4 o = {(_Float16)acc[mt][nt][0], (_Float16)acc[mt][nt][1],
                (_Float16)acc[mt][nt][2], (_Float16)acc[mt][nt][3]};
        *(h4*)(buf + (((size_t)b * NH + h) * NN + token) * 64 + dh) = o;
      }
    }
  } else {
    const int h = ((d0 - 2 * DD) >> 6) + wm;
#pragma unroll
    for (int mt = 0; mt < 4; ++mt) {
      const int dh = mt * 16 + l15;
#pragma unroll
      for (int nt = 0; nt < 4; ++nt) {
        const int token = n0 + wn * 64 + nt * 16 + quad * 4;
        h4 o = {(_Float16)acc[mt][nt][0], (_Float16)acc[mt][nt][1],
                (_Float16)acc[mt][nt][2], (_Float16)acc[mt][nt][3]};
        *(h4*)(vb + (((size_t)b * NH + h) * 64 + dh) * NN + token) = o;
      }
    }
  }
}

// ---------------------------------------------------------------------------
// Kernel 2: MFMA flash attention (unchanged from R2 except f16 ho output).
// ---------------------------------------------------------------------------
__global__ __launch_bounds__(128, 2) void attn_k(
    const _Float16* __restrict__ qb, const _Float16* __restrict__ kb,
    const _Float16* __restrict__ vb, const _Float16* __restrict__ bt,
    _Float16* __restrict__ ho)
{
  __shared__ _Float16 Ks[64][72];
  __shared__ _Float16 Vs[64][72];
  __shared__ _Float16 Bs[64][72];
  __shared__ _Float16 Ps[64][72];

  const int t    = threadIdx.x;
  const int lane = t & 63;
  const int w    = t >> 6;
  const int l15  = lane & 15;
  const int quad = lane >> 4;
  const int n0 = blockIdx.x * 64;
  const int h  = blockIdx.y;
  const int b  = blockIdx.z;
  const size_t base = ((size_t)b * NH + h) * NN * 64;
  const _Float16* qp = qb + base;
  const _Float16* kp = kb + base;
  const _Float16* vp = vb + base;  // [dh][n]

  h8 qf[2][2];
#pragma unroll
  for (int nt = 0; nt < 2; ++nt)
#pragma unroll
    for (int ks = 0; ks < 2; ++ks)
      qf[nt][ks] = *(const h8*)(qp + (size_t)(n0 + w * 32 + nt * 16 + l15) * 64 +
                                ks * 32 + quad * 8);

  f4 oc[4][2];
#pragma unroll
  for (int mt = 0; mt < 4; ++mt)
#pragma unroll
    for (int nt = 0; nt < 2; ++nt) oc[mt][nt] = (f4)(0.f);
  float mx[2] = {-INFINITY, -INFINITY};
  float ls[2] = {0.f, 0.f};

  for (int k0 = 0; k0 < NN; k0 += 64) {
    h8 kr[4], vr[4], br[4];
#pragma unroll
    for (int r = 0; r < 4; ++r) {
      const int c = t + r * 128;
      const int row = c >> 3, off = (c & 7) * 8;
      kr[r] = *(const h8*)(kp + (size_t)(k0 + row) * 64 + off);
      vr[r] = *(const h8*)(vp + (size_t)row * NN + k0 + off);
      br[r] = *(const h8*)(bt + (size_t)(n0 + row) * NN + k0 + off);
    }
    __syncthreads();
#pragma unroll
    for (int r = 0; r < 4; ++r) {
      const int c = t + r * 128;
      const int row = c >> 3, off = (c & 7) * 8;
      *(h8*)&Ks[row][off] = kr[r];
      *(h8*)&Vs[row][off] = vr[r];
      *(h8*)&Bs[row][off] = br[r];
    }
    __syncthreads();

    f4 st[4][2];
#pragma unroll
    for (int mt = 0; mt < 4; ++mt)
#pragma unroll
      for (int nt = 0; nt < 2; ++nt) st[mt][nt] = (f4)(0.f);
#pragma unroll
    for (int ks = 0; ks < 2; ++ks) {
#pragma unroll
      for (int mt = 0; mt < 4; ++mt) {
        h8 kf = *(const h8*)&Ks[mt * 16 + l15][ks * 32 + quad * 8];
#pragma unroll
        for (int nt = 0; nt < 2; ++nt)
          st[mt][nt] = __builtin_amdgcn_mfma_f32_16x16x32_f16(
              kf, qf[nt][ks], st[mt][nt], 0, 0, 0);
      }
    }

#pragma unroll
    for (int nt = 0; nt < 2; ++nt) {
      const int q = w * 32 + nt * 16 + l15;
      float lg[4][4];
      float rowmax = -INFINITY;
#pragma unroll
      for (int mt = 0; mt < 4; ++mt) {
        h4 bv = *(const h4*)&Bs[q][mt * 16 + quad * 4];
#pragma unroll
        for (int r = 0; r < 4; ++r) {
          float v = st[mt][nt][r] * 0.125f + (float)bv[r];
          lg[mt][r] = v;
          rowmax = fmaxf(rowmax, v);
        }
      }
      rowmax = fmaxf(rowmax, __shfl_xor(rowmax, 16));
      rowmax = fmaxf(rowmax, __shfl_xor(rowmax, 32));
      const float mnew = fmaxf(mx[nt], rowmax);
      const float alpha = __expf(mx[nt] - mnew);
      mx[nt] = mnew;
      float psum = 0.f;
#pragma unroll
      for (int mt = 0; mt < 4; ++mt) {
        h4 pk;
#pragma unroll
        for (int r = 0; r < 4; ++r) {
          float p = __expf(lg[mt][r] - mnew);
          psum += p;
          pk[r] = (_Float16)p;
        }
        *(h4*)&Ps[q][mt * 16 + quad * 4] = pk;
      }
      psum += __shfl_xor(psum, 16);
      psum += __shfl_xor(psum, 32);
      ls[nt] = ls[nt] * alpha + psum;
#pragma unroll
      for (int mt = 0; mt < 4; ++mt)
#pragma unroll
        for (int r = 0; r < 4; ++r) oc[mt][nt][r] *= alpha;
    }

#pragma unroll
    for (int ks = 0; ks < 2; ++ks) {
      h8 pf[2];
#pragma unroll
      for (int nt = 0; nt < 2; ++nt)
        pf[nt] = *(const h8*)&Ps[w * 32 + nt * 16 + l15][ks * 32 + quad * 8];
#pragma unroll
      for (int mt = 0; mt < 4; ++mt) {
        h8 vf = *(const h8*)&Vs[mt * 16 + l15][ks * 32 + quad * 8];
#pragma unroll
        for (int nt = 0; nt < 2; ++nt)
          oc[mt][nt] = __builtin_amdgcn_mfma_f32_16x16x32_f16(
              vf, pf[nt], oc[mt][nt], 0, 0, 0);
      }
    }
  }

#pragma unroll
  for (int nt = 0; nt < 2; ++nt) {
    const float inv = 1.f / ls[nt];
    const int qi = n0 + w * 32 + nt * 16 + l15;
#pragma unroll
    for (int mt = 0; mt < 4; ++mt) {
      const int dh = mt * 16 + quad * 4;
      h4 o = {(_Float16)(oc[mt][nt][0] * inv), (_Float16)(oc[mt][nt][1] * inv),
              (_Float16)(oc[mt][nt][2] * inv), (_Float16)(oc[mt][nt][3] * inv)};
      *(h4*)(ho + ((size_t)b * NN + qi) * DD + h * 64 + dh) = o;
    }
  }
}

// ---------------------------------------------------------------------------
// Kernel 3: out MFMA GEMM. out[b][o][n] = sum_d ho[n][d]*woh[o][d] + bias[o].
// 64x64 tile per single-wave block; D[token][o] -> float4 packs along n.
// ---------------------------------------------------------------------------
__global__ __launch_bounds__(64) void out_gemm_k(
    const _Float16* __restrict__ ho, const _Float16* __restrict__ woh,
    const float* __restrict__ bias, float* __restrict__ out)
{
  __shared__ _Float16 Hs[64][32];
  __shared__ _Float16 Ws2[64][32];
  const int t = threadIdx.x;
  const int l15 = t & 15, quad = t >> 4;
  const int n0 = blockIdx.x * 64;
  const int o0 = blockIdx.y * 64;
  const int b  = blockIdx.z;
  const int srow = t >> 2, scol = (t & 3) * 8;

  f4 acc[4][4];
#pragma unroll
  for (int mt = 0; mt < 4; ++mt)
#pragma unroll
    for (int nt = 0; nt < 4; ++nt) acc[mt][nt] = (f4)(0.f);

  for (int c0 = 0; c0 < DD; c0 += 32) {
#pragma unroll
    for (int ci = 0; ci < 4; ++ci) {
      const int row = ci * 16 + srow;
      gload16(ho + ((size_t)b * NN + n0 + row) * DD + c0 + scol,
              &Hs[0][0] + ci * 512);
      gload16(woh + (size_t)(o0 + row) * DD + c0 + scol,
              &Ws2[0][0] + ci * 512);
    }
    __syncthreads();
    h8 hf[4], wf[4];
#pragma unroll
    for (int mt = 0; mt < 4; ++mt)
      hf[mt] = *(const h8*)&Hs[mt * 16 + l15][quad * 8];
#pragma unroll
    for (int nt = 0; nt < 4; ++nt)
      wf[nt] = *(const h8*)&Ws2[nt * 16 + l15][quad * 8];
#pragma unroll
    for (int mt = 0; mt < 4; ++mt)
#pragma unroll
      for (int nt = 0; nt < 4; ++nt)
        acc[mt][nt] = __builtin_amdgcn_mfma_f32_16x16x32_f16(
            hf[mt], wf[nt], acc[mt][nt], 0, 0, 0);
    __syncthreads();
  }

#pragma unroll
  for (int nt = 0; nt < 4; ++nt) {
    const int o = o0 + nt * 16 + l15;
    const float bv = bias[o];
#pragma unroll
    for (int mt = 0; mt < 4; ++mt) {
      const int token = n0 + mt * 16 + quad * 4;
      float4 v = {acc[mt][nt][0] + bv, acc[mt][nt][1] + bv,
                  acc[mt][nt][2] + bv, acc[mt][nt][3] + bv};
      *(float4*)(out + ((size_t)b * DD + o) * NN + token) = v;
    }
  }
}

extern "C" void kernel_launch(void* const* d_in, const int* in_sizes, int n_in,
                              void* d_out, int out_size, void* d_ws, size_t ws_size,
                              hipStream_t stream)
{
  (void)in_sizes; (void)n_in; (void)out_size; (void)ws_size;
  const float* x     = (const float*)d_in[0];
  const float* w_qkv = (const float*)d_in[1];
  const float* w_out = (const float*)d_in[2];
  const float* b_out = (const float*)d_in[3];
  const float* wav   = (const float*)d_in[4];
  float* out = (float*)d_out;

  const size_t SZ = (size_t)BB * NH * NN * 64;  // 2,359,296
  _Float16* qb  = (_Float16*)d_ws;
  _Float16* kb  = qb + SZ;
  _Float16* vb  = kb + SZ;
  _Float16* bt  = vb + SZ;                         // 2304*2304
  _Float16* xt  = bt + (size_t)NN * NN;            // [b][n][c]
  _Float16* wqh = xt + SZ;                         // [1536][512]
  _Float16* woh = wqh + (size_t)D3 * CC;           // [512][512]
  _Float16* ho  = woh + (size_t)DD * DD;           // [b][n][512]
  // total: 18,153,472 f16 = 36.3 MB

  bias_k    <<<dim3(NN / 256, NN), 256, 0, stream>>>(wav, bt);
  tx_k      <<<dim3(NN / 32, CC / 32, BB), 256, 0, stream>>>(x, xt);
  convw_k   <<<dim3((D3 * CC + DD * DD) / 1024), 256, 0, stream>>>(w_qkv, w_out, wqh, woh);
  qkv_gemm_k<<<dim3(NN / 128, D3 / 128, BB), 256, 0, stream>>>(xt, wqh, qb, kb, vb);
  attn_k    <<<dim3(NN / 64, NH, BB), 128, 0, stream>>>(qb, kb, vb, bt, ho);
  out_gemm_k<<<dim3(NN / 64, DD / 64, BB), 64, 0, stream>>>(ho, woh, b_out, out);
}

// Round 4
// 169.286 us; speedup vs baseline: 6.3113x; 1.1286x over previous
//
#include <hip/hip_runtime.h>
#include <math.h>

#define BB 2
#define CC 512
#define NN 2304
#define NH 8
#define DD 512
#define D3 1536
#define WIDTH 48
#define C1 0.18033688f  // 0.125 * log2(e)

typedef _Float16 h8 __attribute__((ext_vector_type(8)));
typedef _Float16 h4 __attribute__((ext_vector_type(4)));
typedef _Float16 h2 __attribute__((ext_vector_type(2)));
typedef float f4 __attribute__((ext_vector_type(4)));

__device__ __forceinline__ void gload16(const void* g, void* s) {
  __builtin_amdgcn_global_load_lds(
      (const __attribute__((address_space(1))) unsigned int*)g,
      (__attribute__((address_space(3))) unsigned int*)s, 16, 0, 0);
}

// ---------------------------------------------------------------------------
// Kernel 0: Fresnel bias table in MFMA C-fragment order, pre-scaled by log2e.
// btf[qtile 36][ktile 36][tid 128][j 32], j = nt*16 + mt*4 + r:
//   query = qtile*64 + (tid>>6)*32 + nt*16 + (tid&15)
//   key   = ktile*64 + mt*16 + ((tid>>4)&3)*4 + r
// ---------------------------------------------------------------------------
__global__ __launch_bounds__(128) void btf_k(const float* __restrict__ wavp,
                                             _Float16* __restrict__ btf)
{
  const int t = threadIdx.x;
  const int qbk = blockIdx.x, ktk = blockIdx.y;
  const int w = t >> 6, quad = (t >> 4) & 3, l15 = t & 15;
  const float pc = 6.283185307179586f / (fabsf(wavp[0]) * (float)WIDTH + 1e-6f);
  _Float16* o = btf + (((size_t)qbk * 36 + ktk) * 128 + t) * 32;
#pragma unroll
  for (int g = 0; g < 4; ++g) {
    h8 v;
#pragma unroll
    for (int e = 0; e < 8; ++e) {
      const int j = g * 8 + e;
      const int nt = j >> 4, mt = (j >> 2) & 3, r = j & 3;
      const int q = qbk * 64 + w * 32 + nt * 16 + l15;
      const int k = ktk * 64 + mt * 16 + quad * 4 + r;
      const float dy = (float)(q / WIDTH) - (float)(k / WIDTH);
      const float dx = (float)(q % WIDTH) - (float)(k % WIDTH);
      const float dist = sqrtf(dy * dy + dx * dx + 1e-8f);
      v[e] = (_Float16)(0.1f * __cosf(dist * pc) * 1.44269504f);
    }
    *(h8*)(o + g * 8) = v;
  }
}

// ---------------------------------------------------------------------------
// Kernel 0b: transpose-convert x[b][c][n] fp32 -> xt[b][n][c] f16
// ---------------------------------------------------------------------------
__global__ __launch_bounds__(256) void tx_k(const float* __restrict__ x,
                                            _Float16* __restrict__ xt)
{
  __shared__ float Ls[32][33];
  const int t = threadIdx.x;
  const int n0 = blockIdx.x * 32, c0 = blockIdx.y * 32, b = blockIdx.z;
#pragma unroll
  for (int p = 0; p < 4; ++p) {
    const int cl = (t >> 5) + p * 8, nl = t & 31;
    Ls[cl][nl] = x[((size_t)b * CC + c0 + cl) * NN + n0 + nl];
  }
  __syncthreads();
#pragma unroll
  for (int p = 0; p < 2; ++p) {
    const int nl = (t >> 4) + p * 16, cl = (t & 15) * 2;
    h2 v = {(_Float16)Ls[cl][nl], (_Float16)Ls[cl + 1][nl]};
    *(h2*)(xt + ((size_t)b * NN + n0 + nl) * CC + c0 + cl) = v;
  }
}

// ---------------------------------------------------------------------------
// Kernel 0c: convert w_qkv and w_out fp32 -> f16
// ---------------------------------------------------------------------------
__global__ __launch_bounds__(256) void convw_k(const float* __restrict__ wq,
                                               const float* __restrict__ wo,
                                               _Float16* __restrict__ wqh,
                                               _Float16* __restrict__ woh)
{
  const int idx = blockIdx.x * 256 + threadIdx.x;
  const int NQ = (D3 * CC) / 4;
  if (idx < NQ) {
    float4 v = *(const float4*)(wq + (size_t)idx * 4);
    h4 o = {(_Float16)v.x, (_Float16)v.y, (_Float16)v.z, (_Float16)v.w};
    *(h4*)(wqh + (size_t)idx * 4) = o;
  } else {
    const int j = idx - NQ;
    float4 v = *(const float4*)(wo + (size_t)j * 4);
    h4 o = {(_Float16)v.x, (_Float16)v.y, (_Float16)v.z, (_Float16)v.w};
    *(h4*)(woh + (size_t)j * 4) = o;
  }
}

// ---------------------------------------------------------------------------
// Kernel 1: qkv MFMA GEMM (unchanged from R3).
// ---------------------------------------------------------------------------
__global__ __launch_bounds__(256) void qkv_gemm_k(
    const _Float16* __restrict__ xt, const _Float16* __restrict__ wqh,
    _Float16* __restrict__ qb, _Float16* __restrict__ kb,
    _Float16* __restrict__ vb)
{
  __shared__ _Float16 Xs[128][32];
  __shared__ _Float16 Ws[128][32];
  const int t = threadIdx.x;
  const int lane = t & 63, w = t >> 6;
  const int l15 = lane & 15, quad = lane >> 4;
  const int wm = w & 1, wn = w >> 1;
  const int n0 = blockIdx.x * 128;
  const int d0 = blockIdx.y * 128;
  const int b  = blockIdx.z;
  const bool isv = (d0 >= 2 * DD);
  const _Float16* xb = xt + (size_t)b * NN * CC;

  const int srow = lane >> 2, scol = (lane & 3) * 8;

  f4 acc[4][4];
#pragma unroll
  for (int mt = 0; mt < 4; ++mt)
#pragma unroll
    for (int nt = 0; nt < 4; ++nt) acc[mt][nt] = (f4)(0.f);

  for (int c0 = 0; c0 < CC; c0 += 32) {
#pragma unroll
    for (int r = 0; r < 2; ++r) {
      const int ci = w + r * 4;
      const int row = ci * 16 + srow;
      gload16(xb + (size_t)(n0 + row) * CC + c0 + scol, &Xs[0][0] + ci * 512);
      gload16(wqh + (size_t)(d0 + row) * CC + c0 + scol, &Ws[0][0] + ci * 512);
    }
    __syncthreads();

    h8 wfr[4], xfr[4];
#pragma unroll
    for (int mt = 0; mt < 4; ++mt)
      wfr[mt] = *(const h8*)&Ws[wm * 64 + mt * 16 + l15][quad * 8];
#pragma unroll
    for (int nt = 0; nt < 4; ++nt)
      xfr[nt] = *(const h8*)&Xs[wn * 64 + nt * 16 + l15][quad * 8];

    if (!isv) {
#pragma unroll
      for (int mt = 0; mt < 4; ++mt)
#pragma unroll
        for (int nt = 0; nt < 4; ++nt)
          acc[mt][nt] = __builtin_amdgcn_mfma_f32_16x16x32_f16(
              wfr[mt], xfr[nt], acc[mt][nt], 0, 0, 0);
    } else {
#pragma unroll
      for (int mt = 0; mt < 4; ++mt)
#pragma unroll
        for (int nt = 0; nt < 4; ++nt)
          acc[mt][nt] = __builtin_amdgcn_mfma_f32_16x16x32_f16(
              xfr[nt], wfr[mt], acc[mt][nt], 0, 0, 0);
    }
    __syncthreads();
  }

  if (!isv) {
    const int which = d0 >> 9;
    _Float16* buf = which == 0 ? qb : kb;
    const int h = ((d0 & 511) >> 6) + wm;
#pragma unroll
    for (int mt = 0; mt < 4; ++mt) {
      const int dh = mt * 16 + quad * 4;
#pragma unroll
      for (int nt = 0; nt < 4; ++nt) {
        const int token = n0 + wn * 64 + nt * 16 + l15;
        h4 o = {(_Float16)acc[mt][nt][0], (_Float16)acc[mt][nt][1],
                (_Float16)acc[mt][nt][2], (_Float16)acc[mt][nt][3]};
        *(h4*)(buf + (((size_t)b * NH + h) * NN + token) * 64 + dh) = o;
      }
    }
  } else {
    const int h = ((d0 - 2 * DD) >> 6) + wm;
#pragma unroll
    for (int mt = 0; mt < 4; ++mt) {
      const int dh = mt * 16 + l15;
#pragma unroll
      for (int nt = 0; nt < 4; ++nt) {
        const int token = n0 + wn * 64 + nt * 16 + quad * 4;
        h4 o = {(_Float16)acc[mt][nt][0], (_Float16)acc[mt][nt][1],
                (_Float16)acc[mt][nt][2], (_Float16)acc[mt][nt][3]};
        *(h4*)(vb + (((size_t)b * NH + h) * 64 + dh) * NN + token) = o;
      }
    }
  }
}

// ---------------------------------------------------------------------------
// Kernel 2: MFMA flash attention, K-split x2, no-max softmax (p = exp2(s)),
// bias read directly from frag-ordered global table. Writes normalized O/l
// partials (f16) + l partials (f32).
// ---------------------------------------------------------------------------
__global__ __launch_bounds__(128, 3) void attn_k(
    const _Float16* __restrict__ qb, const _Float16* __restrict__ kb,
    const _Float16* __restrict__ vb, const _Float16* __restrict__ btf,
    _Float16* __restrict__ op, float* __restrict__ lp)
{
  __shared__ _Float16 Ks[64][72];
  __shared__ _Float16 Vs[64][72];
  __shared__ _Float16 Ps[64][72];

  const int t    = threadIdx.x;
  const int lane = t & 63;
  const int w    = t >> 6;
  const int l15  = lane & 15;
  const int quad = lane >> 4;
  const int qtile = blockIdx.x >> 1;
  const int khalf = blockIdx.x & 1;
  const int n0 = qtile * 64;
  const int h  = blockIdx.y;
  const int b  = blockIdx.z;
  const size_t base = ((size_t)b * NH + h) * NN * 64;
  const _Float16* qp = qb + base;
  const _Float16* kp = kb + base;
  const _Float16* vp = vb + base;  // [dh][n]

  h8 qf[2][2];
#pragma unroll
  for (int nt = 0; nt < 2; ++nt)
#pragma unroll
    for (int ks = 0; ks < 2; ++ks)
      qf[nt][ks] = *(const h8*)(qp + (size_t)(n0 + w * 32 + nt * 16 + l15) * 64 +
                                ks * 32 + quad * 8);

  f4 oc[4][2];
#pragma unroll
  for (int mt = 0; mt < 4; ++mt)
#pragma unroll
    for (int nt = 0; nt < 2; ++nt) oc[mt][nt] = (f4)(0.f);
  float lacc[2][4] = {};

  const _Float16* bp = btf + (((size_t)qtile * 36 + khalf * 18) * 128 + t) * 32;

  for (int kt = 0; kt < 18; ++kt) {
    const int k0 = (khalf * 18 + kt) * 64;
    h8 kr[4], vr[4], bfr[4];
#pragma unroll
    for (int r = 0; r < 4; ++r) {
      const int c = t + r * 128;
      const int row = c >> 3, off = (c & 7) * 8;
      kr[r] = *(const h8*)(kp + (size_t)(k0 + row) * 64 + off);
      vr[r] = *(const h8*)(vp + (size_t)row * NN + k0 + off);
      bfr[r] = *(const h8*)(bp + r * 8);
    }
    bp += 128 * 32;
    __syncthreads();
#pragma unroll
    for (int r = 0; r < 4; ++r) {
      const int c = t + r * 128;
      const int row = c >> 3, off = (c & 7) * 8;
      *(h8*)&Ks[row][off] = kr[r];
      *(h8*)&Vs[row][off] = vr[r];
    }
    __syncthreads();

    // ---- S^T = K * Q^T ----
    f4 st[4][2];
#pragma unroll
    for (int mt = 0; mt < 4; ++mt)
#pragma unroll
      for (int nt = 0; nt < 2; ++nt) st[mt][nt] = (f4)(0.f);
#pragma unroll
    for (int ks = 0; ks < 2; ++ks) {
#pragma unroll
      for (int mt = 0; mt < 4; ++mt) {
        h8 kf = *(const h8*)&Ks[mt * 16 + l15][ks * 32 + quad * 8];
#pragma unroll
        for (int nt = 0; nt < 2; ++nt)
          st[mt][nt] = __builtin_amdgcn_mfma_f32_16x16x32_f16(
              kf, qf[nt][ks], st[mt][nt], 0, 0, 0);
      }
    }

    // ---- p = exp2(s*C1 + bias'), no max tracking ----
#pragma unroll
    for (int nt = 0; nt < 2; ++nt) {
      const int q = w * 32 + nt * 16 + l15;
#pragma unroll
      for (int mt = 0; mt < 4; ++mt) {
        h4 pk;
#pragma unroll
        for (int r = 0; r < 4; ++r) {
          const int j = nt * 16 + mt * 4 + r;
          const float bias = (float)bfr[j >> 3][j & 7];
          const float p = __builtin_exp2f(st[mt][nt][r] * C1 + bias);
          lacc[nt][r] += p;
          pk[r] = (_Float16)p;
        }
        *(h4*)&Ps[q][mt * 16 + quad * 4] = pk;  // wave-private rows
      }
    }

    // ---- O^T += V^T * P^T ----
#pragma unroll
    for (int ks = 0; ks < 2; ++ks) {
      h8 pf[2];
#pragma unroll
      for (int nt = 0; nt < 2; ++nt)
        pf[nt] = *(const h8*)&Ps[w * 32 + nt * 16 + l15][ks * 32 + quad * 8];
#pragma unroll
      for (int mt = 0; mt < 4; ++mt) {
        h8 vf = *(const h8*)&Vs[mt * 16 + l15][ks * 32 + quad * 8];
#pragma unroll
        for (int nt = 0; nt < 2; ++nt)
          oc[mt][nt] = __builtin_amdgcn_mfma_f32_16x16x32_f16(
              vf, pf[nt], oc[mt][nt], 0, 0, 0);
      }
    }
  }

  // ---- epilogue: reduce l across quads, write O/l (f16) + l (f32) ----
#pragma unroll
  for (int nt = 0; nt < 2; ++nt) {
    float l = lacc[nt][0] + lacc[nt][1] + lacc[nt][2] + lacc[nt][3];
    l += __shfl_xor(l, 16);
    l += __shfl_xor(l, 32);
    const float inv = 1.f / l;
    const int qi = n0 + w * 32 + nt * 16 + l15;
    _Float16* od = op + (size_t)khalf * BB * NN * DD +
                   ((size_t)b * NN + qi) * DD + h * 64;
#pragma unroll
    for (int mt = 0; mt < 4; ++mt) {
      const int dh = mt * 16 + quad * 4;
      h4 o = {(_Float16)(oc[mt][nt][0] * inv), (_Float16)(oc[mt][nt][1] * inv),
              (_Float16)(oc[mt][nt][2] * inv), (_Float16)(oc[mt][nt][3] * inv)};
      *(h4*)(od + dh) = o;
    }
    if (quad == 0)
      lp[(size_t)khalf * BB * NH * NN + ((size_t)b * NH + h) * NN + qi] = l;
  }
}

// ---------------------------------------------------------------------------
// Kernel 2b: combine K-split halves: ho = (o0*l0 + o1*l1) / (l0+l1)
// ---------------------------------------------------------------------------
__global__ __launch_bounds__(256) void comb_k(
    const _Float16* __restrict__ op, const float* __restrict__ lp,
    _Float16* __restrict__ ho)
{
  const int idx = blockIdx.x * 256 + threadIdx.x;  // B*NN*64
  const int d8 = idx & 63;
  const int bn = idx >> 6;
  const int n = bn % NN, b = bn / NN;
  const int h = d8 >> 3;
  const float l0 = lp[((size_t)b * NH + h) * NN + n];
  const float l1 = lp[(size_t)BB * NH * NN + ((size_t)b * NH + h) * NN + n];
  const float inv = 1.f / (l0 + l1);
  const float w0 = l0 * inv, w1 = l1 * inv;
  h8 o0 = *(const h8*)(op + (size_t)bn * DD + d8 * 8);
  h8 o1 = *(const h8*)(op + (size_t)BB * NN * DD + (size_t)bn * DD + d8 * 8);
  h8 r;
#pragma unroll
  for (int i = 0; i < 8; ++i)
    r[i] = (_Float16)((float)o0[i] * w0 + (float)o1[i] * w1);
  *(h8*)(ho + (size_t)bn * DD + d8 * 8) = r;
}

// ---------------------------------------------------------------------------
// Kernel 3: out MFMA GEMM (unchanged from R3).
// ---------------------------------------------------------------------------
__global__ __launch_bounds__(64) void out_gemm_k(
    const _Float16* __restrict__ ho, const _Float16* __restrict__ woh,
    const float* __restrict__ bias, float* __restrict__ out)
{
  __shared__ _Float16 Hs[64][32];
  __shared__ _Float16 Ws2[64][32];
  const int t = threadIdx.x;
  const int l15 = t & 15, quad = t >> 4;
  const int n0 = blockIdx.x * 64;
  const int o0 = blockIdx.y * 64;
  const int b  = blockIdx.z;
  const int srow = t >> 2, scol = (t & 3) * 8;

  f4 acc[4][4];
#pragma unroll
  for (int mt = 0; mt < 4; ++mt)
#pragma unroll
    for (int nt = 0; nt < 4; ++nt) acc[mt][nt] = (f4)(0.f);

  for (int c0 = 0; c0 < DD; c0 += 32) {
#pragma unroll
    for (int ci = 0; ci < 4; ++ci) {
      const int row = ci * 16 + srow;
      gload16(ho + ((size_t)b * NN + n0 + row) * DD + c0 + scol,
              &Hs[0][0] + ci * 512);
      gload16(woh + (size_t)(o0 + row) * DD + c0 + scol,
              &Ws2[0][0] + ci * 512);
    }
    __syncthreads();
    h8 hf[4], wf[4];
#pragma unroll
    for (int mt = 0; mt < 4; ++mt)
      hf[mt] = *(const h8*)&Hs[mt * 16 + l15][quad * 8];
#pragma unroll
    for (int nt = 0; nt < 4; ++nt)
      wf[nt] = *(const h8*)&Ws2[nt * 16 + l15][quad * 8];
#pragma unroll
    for (int mt = 0; mt < 4; ++mt)
#pragma unroll
      for (int nt = 0; nt < 4; ++nt)
        acc[mt][nt] = __builtin_amdgcn_mfma_f32_16x16x32_f16(
            hf[mt], wf[nt], acc[mt][nt], 0, 0, 0);
    __syncthreads();
  }

#pragma unroll
  for (int nt = 0; nt < 4; ++nt) {
    const int o = o0 + nt * 16 + l15;
    const float bv = bias[o];
#pragma unroll
    for (int mt = 0; mt < 4; ++mt) {
      const int token = n0 + mt * 16 + quad * 4;
      float4 v = {acc[mt][nt][0] + bv, acc[mt][nt][1] + bv,
                  acc[mt][nt][2] + bv, acc[mt][nt][3] + bv};
      *(float4*)(out + ((size_t)b * DD + o) * NN + token) = v;
    }
  }
}

extern "C" void kernel_launch(void* const* d_in, const int* in_sizes, int n_in,
                              void* d_out, int out_size, void* d_ws, size_t ws_size,
                              hipStream_t stream)
{
  (void)in_sizes; (void)n_in; (void)out_size; (void)ws_size;
  const float* x     = (const float*)d_in[0];
  const float* w_qkv = (const float*)d_in[1];
  const float* w_out = (const float*)d_in[2];
  const float* b_out = (const float*)d_in[3];
  const float* wav   = (const float*)d_in[4];
  float* out = (float*)d_out;

  const size_t SZ  = (size_t)BB * NH * NN * 64;   // 2,359,296
  const size_t BTF = (size_t)36 * 36 * 128 * 32;  // 5,308,416

  _Float16* qb  = (_Float16*)d_ws;
  _Float16* kb  = qb + SZ;
  _Float16* vb  = kb + SZ;
  _Float16* btf = vb + SZ;            // 5.3M h; later aliased by ho
  _Float16* op  = btf + BTF;          // 2*SZ partial O (f16, normalized)
  float*    lpf = (float*)(op + 2 * SZ);  // 2*B*NH*NN f32
  _Float16* woh = (_Float16*)(lpf + 2 * (size_t)BB * NH * NN);
  // aliases (lifetime-disjoint):
  _Float16* ho  = btf;       // combine output (btf dead after attn)
  _Float16* xt  = op;        // x^T f16 (dead after qkv_gemm; op written by attn)
  _Float16* wqh = op + SZ;   // w_qkv f16 (dead after qkv_gemm)
  // total ws: 3*SZ + BTF + 2*SZ + lp + woh = ~35.0 MB

  btf_k     <<<dim3(36, 36), 128, 0, stream>>>(wav, btf);
  tx_k      <<<dim3(NN / 32, CC / 32, BB), 256, 0, stream>>>(x, xt);
  convw_k   <<<dim3((D3 * CC + DD * DD) / 1024), 256, 0, stream>>>(w_qkv, w_out, wqh, woh);
  qkv_gemm_k<<<dim3(NN / 128, D3 / 128, BB), 256, 0, stream>>>(xt, wqh, qb, kb, vb);
  attn_k    <<<dim3(NN / 64 * 2, NH, BB), 128, 0, stream>>>(qb, kb, vb, btf, op, lpf);
  comb_k    <<<dim3((BB * NN * 64) / 256), 256, 0, stream>>>(op, lpf, ho);
  out_gemm_k<<<dim3(NN / 64, DD / 64, BB), 64, 0, stream>>>(ho, woh, b_out, out);
}